// Round 5
// baseline (210.962 us; speedup 1.0000x reference)
//
#include <hip/hip_runtime.h>
#include <stdint.h>

#define NUM_CLASSES 80u
#define TOPK 1000
#define CONF_T 0.05f
#define NMS_T 0.6f
#define MAX_COORD 4096.0f
#define TARGET 1152u            // top-1000 + tie/superset slack
#define CAP 49152u              // linear candidate buffer capacity
#define SRVCAP 2048u            // survivor buffer (>= TARGET + boundary ties)
#define STATIC_F 4.0f           // static candidate prefilter threshold
#define STATIC_KEY 0xC0800000u  // fkey(+4.0f)
#define NBINS 4096              // spread bins: (k - STATIC_KEY) >> 13
#define BINSH 13
#define LCAP 512u               // per-block LDS candidate staging (kA)
#define PBLK 1024u              // per-block survivor staging (kSel)

typedef unsigned long long ull;
typedef ull ull2 __attribute__((ext_vector_type(2)));

// Monotone float->uint key: descending float == descending key
__device__ __forceinline__ uint32_t fkey(float x) {
  uint32_t k = __float_as_uint(x);
  return (k & 0x80000000u) ? ~k : (k | 0x80000000u);
}

// Inclusive suffix sum of per-thread v across 256 threads (2 barriers).
__device__ __forceinline__ uint32_t suffix_scan_256(uint32_t v, uint32_t* part,
                                                    int t) {
  int lane = t & 63, wid = t >> 6;  // 4 waves
#pragma unroll
  for (int off = 1; off < 64; off <<= 1) {
    uint32_t x = __shfl_down(v, off);
    if (lane + off < 64) v += x;
  }
  if (lane == 0) part[wid] = v;  // wave totals
  __syncthreads();
  if (wid == 0 && lane < 4) {
    uint32_t pv = part[lane];
#pragma unroll
    for (int off = 1; off < 4; off <<= 1) {
      uint32_t x = __shfl_down(pv, off);
      if (lane + off < 4) pv += x;
    }
    part[lane] = pv;  // inclusive suffix of wave totals
  }
  __syncthreads();
  uint32_t after = (wid < 3) ? part[wid + 1] : 0u;
  return v + after;
}

// Suffix-scan hl[NBINSX] with 256 threads (contiguous chunk per thread) and
// find the crossing bin for `target`: unique thread writes bin/A/cnt.
// A = count strictly above bin; cnt = hl[bin]; A < target <= A + cnt.
template <int NBINSX>
__device__ __forceinline__ void pick_bin(const uint32_t* hl, uint32_t target,
                                         int t, uint32_t* part, uint32_t* binS,
                                         uint32_t* AS, uint32_t* cntS) {
  const int CH = NBINSX / 256;
  uint32_t s = 0;
#pragma unroll
  for (int j = 0; j < CH; ++j) s += hl[t * CH + j];
  uint32_t incl = suffix_scan_256(s, part, t);
  uint32_t after = incl - s;  // suffix strictly after my chunk
  if (incl >= target && after < target) {  // crossing inside my chunk: unique
    uint32_t cum = after;
    for (int j = CH - 1; j >= 0; --j) {
      uint32_t h = hl[t * CH + j];
      if (cum + h >= target) { *binS = (uint32_t)(t * CH + j); *AS = cum; *cntS = h; break; }
      cum += h;
    }
  }
}

// ---------------- kernel Z: zero hist+sel, prefill outputs ----------------
__global__ void __launch_bounds__(256) kz(uint32_t* hist, uint32_t* sel,
                                          float* out, float* topScore) {
  int g = blockIdx.x * 256 + threadIdx.x;  // 16 x 256 = 4096
  hist[g] = 0u;
  if (g < 16) sel[g] = 0u;
  for (int i = g; i < 4000; i += 4096) out[i] = 0.0f;  // boxes prefill
  if (g < 1000) { out[5000 + g] = 0.0f; topScore[g] = 0.0f; }  // labels/scores
}

// ---------------- kernel A: stream + compact + spread-bin histogram -------
// r4 post-mortem: 53us at 815 GB/s, VALUBusy 2.9%, occupancy 30% ->
// latency-bound from (a) 1024-block grid = only 16 waves/CU and (b) one
// 16B load/iter (in-flight bytes << BW-latency product of ~2.4 MB).
// Fix: 2048 blocks (__launch_bounds__(256,8): 8 blocks/CU = 32 waves) and
// 2x float4 per iteration (32 B/lane/iter, two independent loads in
// flight). Candidate handling unchanged: LDS staging + ONE global
// atomicAdd per block; global spread-bin hist (complete even on overflow).
__global__ void __launch_bounds__(256, 8) kA(const float4* __restrict__ cls,
                                             int n4,
                                             uint32_t* __restrict__ sel,
                                             uint32_t* __restrict__ hist,
                                             uint32_t* __restrict__ candKey,
                                             uint32_t* __restrict__ candIdx) {
  __shared__ uint32_t lk[LCAP];
  __shared__ uint32_t li[LCAP];
  __shared__ uint32_t lcnt, gbase;
  if (threadIdx.x == 0) lcnt = 0u;
  __syncthreads();
  int n2 = n4 >> 1;  // float4 pairs
  int stride = gridDim.x * blockDim.x;
  int gid = blockIdx.x * blockDim.x + threadIdx.x;
  for (int i = gid; i < n2; i += stride) {
    float4 a = cls[i * 2];
    float4 b = cls[i * 2 + 1];   // independent loads -> MLP
    float f8[8] = {a.x, a.y, a.z, a.w, b.x, b.y, b.z, b.w};
#pragma unroll
    for (int c = 0; c < 8; ++c) {
      if (f8[c] >= STATIC_F) {
        uint32_t k = fkey(f8[c]);
        uint32_t bb = (k - STATIC_KEY) >> BINSH; if (bb > NBINS - 1u) bb = NBINS - 1u;
        atomicAdd(&hist[bb], 1u);
        uint32_t p = atomicAdd(&lcnt, 1u);  // LDS atomic: cheap, distributed
        if (p < LCAP) { lk[p] = k; li[p] = (uint32_t)i * 8u + c; }
        else {  // spill (correctness-only; ~never taken)
          uint32_t gp = atomicAdd(&sel[2], 1u);
          if (gp < CAP) { candKey[gp] = k; candIdx[gp] = (uint32_t)i * 8u + c; }
        }
      }
    }
  }
  if (gid == 0 && (n4 & 1)) {  // odd-n4 tail (not taken: n4 even on bench)
    float4 v = cls[n4 - 1];
    float f4[4] = {v.x, v.y, v.z, v.w};
    for (int c = 0; c < 4; ++c) {
      if (f4[c] >= STATIC_F) {
        uint32_t k = fkey(f4[c]);
        uint32_t bb = (k - STATIC_KEY) >> BINSH; if (bb > NBINS - 1u) bb = NBINS - 1u;
        atomicAdd(&hist[bb], 1u);
        uint32_t gp = atomicAdd(&sel[2], 1u);
        if (gp < CAP) { candKey[gp] = k; candIdx[gp] = (uint32_t)(n4 - 1) * 4u + c; }
      }
    }
  }
  __syncthreads();
  uint32_t c = lcnt; if (c > LCAP) c = LCAP;
  if (threadIdx.x == 0 && c) gbase = atomicAdd(&sel[2], c);  // ONE per block
  __syncthreads();
  for (uint32_t i = threadIdx.x; i < c; i += 256u) {
    uint32_t gp = gbase + i;
    if (gp < CAP) { candKey[gp] = lk[i]; candIdx[gp] = li[i]; }
  }
}

// ---------------- kernel Sel: multi-block threshold + survivor select -----
// 64 blocks each REDUNDANTLY stage the 16 KB histogram, suffix-scan for the
// crossing bin, set T = bin floor (bin width ~4e-3 in x; TARGET slack
// absorbs the whole bin, no fine refine), then select their slice of
// candidates in parallel (LDS staging + one global atomic/block).
// Survivor order is arbitrary; kF2's ranking is order-independent.
// FALLBACK (n < TARGET or n > CAP; never on bench data): block 0 does the
// full single-block histogram + fine refine + select.
__global__ void __launch_bounds__(256) kSel(
    const float4* __restrict__ cls4, int n4,
    uint32_t* __restrict__ sel, const uint32_t* __restrict__ hist,
    const uint32_t* __restrict__ candKey, const uint32_t* __restrict__ candIdx,
    ull* __restrict__ srv) {
  __shared__ uint32_t hl[NBINS];       // 16 KB
  __shared__ uint32_t part[16];
  __shared__ uint32_t sk_[PBLK];       // staged survivor keys
  __shared__ uint32_t si_[PBLK];       // staged survivor idxs
  __shared__ uint32_t lcnt, gbase, binS, AS, cntS;
  int t = threadIdx.x;
  uint32_t n = sel[2];
  bool fb = (n < TARGET) || (n > CAP);

  if (!fb) {
    for (int i = t; i < NBINS; i += 256) hl[i] = hist[i];
    if (t == 0) { lcnt = 0u; binS = 0u; AS = 0u; cntS = 0u; }
    __syncthreads();
    pick_bin<NBINS>(hl, TARGET, t, part, &binS, &AS, &cntS);
    __syncthreads();
    uint32_t T;
    if (AS + cntS > SRVCAP)            // bin spike (adversarial ties only):
      T = STATIC_KEY + ((binS + 1u) << BINSH);  // take strictly-above set (=AS)
    else
      T = STATIC_KEY + (binS << BINSH);
    uint32_t stride = gridDim.x * blockDim.x;
    for (uint32_t i = blockIdx.x * 256u + (uint32_t)t; i < n; i += stride) {
      uint32_t k = candKey[i];
      if (k >= T) {
        uint32_t p = atomicAdd(&lcnt, 1u);
        if (p < PBLK) { sk_[p] = k; si_[p] = candIdx[i]; }
      }
    }
    __syncthreads();
    uint32_t c = lcnt; if (c > PBLK) c = PBLK;
    if (t == 0 && c) gbase = atomicAdd(&sel[4], c);  // ONE per block
    __syncthreads();
    for (uint32_t i = t; i < c; i += 256u) {
      uint32_t k = sk_[i];
      float x = __uint_as_float(k & 0x7fffffffu);  // all candidates positive
      float p = 1.0f / (1.0f + expf(-x));          // fp32 sigmoid
      uint32_t pos = gbase + i;
      if (pos < SRVCAP)
        srv[pos] = ((ull)__float_as_uint(p) << 32) | (ull)(uint32_t)(~si_[i]);
    }
  } else {
    if (blockIdx.x != 0) return;
    // ---- single-block full fallback ----
    for (int i = t; i < NBINS; i += 256) hl[i] = 0u;
    if (t == 0) { binS = 0u; AS = 0u; cntS = 0u; }
    __syncthreads();
    for (int i = t; i < n4; i += 256) {
      float4 v = cls4[i];
      atomicAdd(&hl[fkey(v.x) >> 20], 1u);
      atomicAdd(&hl[fkey(v.y) >> 20], 1u);
      atomicAdd(&hl[fkey(v.z) >> 20], 1u);
      atomicAdd(&hl[fkey(v.w) >> 20], 1u);
    }
    __syncthreads();
    pick_bin<NBINS>(hl, TARGET, t, part, &binS, &AS, &cntS);  // coarse k>>20
    __syncthreads();
    uint32_t b20 = binS, A = AS;
    for (int i = t; i < 1024; i += 256) hl[i] = 0u;
    if (t == 0) { binS = 0u; }
    __syncthreads();
    for (int i = t; i < n4; i += 256) {  // fine 10-bit hist within b20
      float4 v = cls4[i];
      uint32_t k4[4] = {fkey(v.x), fkey(v.y), fkey(v.z), fkey(v.w)};
#pragma unroll
      for (int c2 = 0; c2 < 4; ++c2)
        if ((k4[c2] >> 20) == b20) atomicAdd(&hl[(k4[c2] >> 10) & 1023u], 1u);
    }
    __syncthreads();
    uint32_t rem = TARGET - A;  // >= 1; fine total = hl-sum >= rem
    pick_bin<1024>(hl, rem, t, part, &binS, &AS, &cntS);
    __syncthreads();
    uint32_t T = (b20 << 20) | (binS << 10);
    for (int i = t; i < n4; i += 256) {
      float4 v = cls4[i];
      uint32_t k4[4] = {fkey(v.x), fkey(v.y), fkey(v.z), fkey(v.w)};
#pragma unroll
      for (int c2 = 0; c2 < 4; ++c2) {
        uint32_t k = k4[c2];
        if (k >= T) {
          uint32_t pos = atomicAdd(&sel[4], 1u);  // perf-irrelevant path
          if (pos < SRVCAP) {
            float x = (k & 0x80000000u) ? __uint_as_float(k & 0x7fffffffu)
                                        : __uint_as_float(~k);
            float p = 1.0f / (1.0f + expf(-x));
            uint32_t idx = (uint32_t)i * 4u + c2;
            srv[pos] = ((ull)__float_as_uint(p) << 32) | (ull)(uint32_t)(~idx);
          }
        }
      }
    }
  }
}

// ---------------- kernel F2: rank survivors + emit ------------------------
// 32 blocks x 64: stage all survivor keys into LDS; thread i computes
// rank_i = #{j: skey_j > skey_i} (exact, ull keys unique via ~idx low bits)
// and emits row rank_i. Order-independent, so kSel's arbitrary survivor
// order is fine. Ties: larger ~idx == smaller idx wins, matching top_k.
__global__ void __launch_bounds__(64) kF2(
    const float* __restrict__ box, const int* __restrict__ ph,
    const int* __restrict__ pw, const uint32_t* __restrict__ sel,
    const ull* __restrict__ srv, float* __restrict__ out,
    float* __restrict__ topScore, float* __restrict__ obox) {
  __shared__ __align__(16) ull sk[SRVCAP];
  int t = threadIdx.x;
  uint32_t scount = sel[4]; if (scount > SRVCAP) scount = SRVCAP;
  uint32_t pad = (scount + 1u) & ~1u;
  for (uint32_t i = t; i < pad; i += 64u) sk[i] = (i < scount) ? srv[i] : 0ull;
  __syncthreads();
  uint32_t i = blockIdx.x * 64u + (uint32_t)t;
  if (i >= scount) return;
  ull my = sk[i];
  uint32_t rank = 0;
#pragma unroll 4
  for (uint32_t j = 0; j < pad; j += 2u) {
    ull2 v = *reinterpret_cast<const ull2*>(&sk[j]);  // b128 broadcast read
    rank += (v.x > my) + (v.y > my);
  }
  if (rank >= TOPK) return;
  uint32_t idx = ~(uint32_t)my;
  float p = __uint_as_float((uint32_t)(my >> 32));
  uint32_t label = idx % NUM_CLASSES;
  uint32_t anchor = idx / NUM_CLASSES;
  float W = (float)pw[0], H = (float)ph[0];
  float b0 = box[anchor * 4u + 0u], b1 = box[anchor * 4u + 1u];
  float b2 = box[anchor * 4u + 2u], b3 = box[anchor * 4u + 3u];
  out[rank * 4 + 0] = fminf(fmaxf(b0 / W, 0.0f), 1.0f);
  out[rank * 4 + 1] = fminf(fmaxf(b1 / H, 0.0f), 1.0f);
  out[rank * 4 + 2] = fminf(fmaxf(b2 / W, 0.0f), 1.0f);
  out[rank * 4 + 3] = fminf(fmaxf(b3 / H, 0.0f), 1.0f);
  out[5000 + rank] = (float)label;
  topScore[rank] = p;
  float off = (float)label * MAX_COORD;  // class-aware NMS offset
  obox[rank * 4 + 0] = b0 + off; obox[rank * 4 + 1] = b1 + off;
  obox[rank * 4 + 2] = b2 + off; obox[rank * 4 + 3] = b3 + off;
}

// ---------------- kernel G: IoU suppression bitmasks (j > i) --------------
__global__ void kG(const float* __restrict__ obox, ull* __restrict__ masks) {
  int i = blockIdx.x;  // row 0..999
  float x1i = obox[i * 4 + 0], y1i = obox[i * 4 + 1];
  float x2i = obox[i * 4 + 2], y2i = obox[i * 4 + 3];
  float ai = (x2i - x1i) * (y2i - y1i);
  for (int base = 0; base < 1024; base += 256) {
    int jj = base + (int)threadIdx.x;
    bool bit = false;
    if (jj < TOPK && jj > i) {
      float x1j = obox[jj * 4 + 0], y1j = obox[jj * 4 + 1];
      float x2j = obox[jj * 4 + 2], y2j = obox[jj * 4 + 3];
      float aj = (x2j - x1j) * (y2j - y1j);
      float ix1 = fmaxf(x1i, x1j), iy1 = fmaxf(y1i, y1j);
      float ix2 = fminf(x2i, x2j), iy2 = fminf(y2i, y2j);
      float iw = fmaxf(ix2 - ix1, 0.0f), ih = fmaxf(iy2 - iy1, 0.0f);
      float inter = iw * ih;
      float iou = inter / (ai + aj - inter + 1e-9f);
      bit = iou > NMS_T;
    }
    ull m = __ballot(bit);
    if ((threadIdx.x & 63u) == 0u) masks[i * 16 + (jj >> 6)] = m;
  }
}

// ---------------- kernel H: LDS-staged single-wave greedy NMS -------------
__global__ void __launch_bounds__(256) kH(const float* __restrict__ topScore,
                                          const ull* __restrict__ masks,
                                          float* __restrict__ out) {
  __shared__ ull lmask[TOPK * 16];
  __shared__ uint32_t nzrow[TOPK];
  __shared__ ull keepsh[16];
  int t = threadIdx.x;
  for (int i = t; i < TOPK; i += 256) nzrow[i] = 0u;
  if (t < 16) keepsh[t] = 0ull;
  __syncthreads();
  for (int i = t; i < TOPK * 16; i += 256) {
    ull m = masks[i];
    lmask[i] = m;
    if (m) atomicOr(&nzrow[i >> 4], 1u);
  }
  for (int base = 0; base < 1024; base += 256) {
    int r = base + t;
    bool v = (r < TOPK) && (topScore[r] > CONF_T);
    ull b = __ballot(v);
    if ((t & 63) == 0) keepsh[(base >> 6) + (t >> 6)] = b;
  }
  __syncthreads();
  if (t < 64) {  // single-wave greedy loop, no barriers inside
    ull kw = (t < 16) ? keepsh[t] : 0ull;
    ull nzw = 0ull;
    if (t < 16) {
      for (int b = 0; b < 64; ++b) {
        int r = t * 64 + b;
        if (r < TOPK && nzrow[r]) nzw |= 1ull << b;
      }
    }
    for (int w = 0; w < 16; ++w) {
      ull cur = __shfl(kw, w) & __shfl(nzw, w);
      while (cur) {
        int b = __ffsll((long long)cur) - 1;
        int i = w * 64 + b;
        if (t < 16) kw &= ~lmask[i * 16 + t];  // row i suppresses only j > i
        ull nk = __shfl(kw, w);
        cur = nk & __shfl(nzw, w);
        cur &= (b == 63) ? 0ull : (~0ull << (b + 1));
      }
    }
    if (t < 16) keepsh[t] = kw;
  }
  __syncthreads();
  for (int r = t; r < TOPK; r += 256) {
    bool k = (keepsh[r >> 6] >> (r & 63)) & 1ull;
    float s = topScore[r];
    out[4000 + r] = k ? s : 0.0f;
    out[6000 + r] = k ? 1.0f : 0.0f;
  }
}

extern "C" void kernel_launch(void* const* d_in, const int* in_sizes, int n_in,
                              void* d_out, int out_size, void* d_ws, size_t ws_size,
                              hipStream_t stream) {
  const float* cls = (const float*)d_in[0];  // (1, N, 80) logits
  const float* box = (const float*)d_in[1];  // (1, N, 4)
  const int* ph = (const int*)d_in[2];       // img_h
  const int* pw = (const int*)d_in[3];       // img_w
  float* out = (float*)d_out;                // [boxes 4000 | scores 1000 | labels 1000 | keep 1000]
  int n = in_sizes[0];                       // 20,971,520 (divisible by 4)

  uint8_t* w = (uint8_t*)d_ws;
  uint32_t* hist    = (uint32_t*)(w);                               // 16 KB
  uint32_t* sel     = (uint32_t*)(w + 16384);                       // 64 B (pad 4 KB)
  uint32_t* candKey = (uint32_t*)(w + 20480);                       // 192 KB
  uint32_t* candIdx = (uint32_t*)(w + 20480 + (size_t)CAP * 4);     // 192 KB
  ull*      srv     = (ull*)     (w + 20480 + (size_t)CAP * 8);     // 16 KB
  float*    topScore= (float*)   (w + 20480 + (size_t)CAP * 8 + 16384);          // 4 KB
  float*    obox    = (float*)   (w + 20480 + (size_t)CAP * 8 + 16384 + 4096);   // 16 KB
  ull*      masks   = (ull*)     (w + 20480 + (size_t)CAP * 8 + 16384 + 4096 + 16384); // 128 KB

  kz  <<<16, 256, 0, stream>>>(hist, sel, out, topScore);
  kA  <<<2048, 256, 0, stream>>>((const float4*)cls, n / 4, sel, hist, candKey, candIdx);
  kSel<<<64, 256, 0, stream>>>((const float4*)cls, n / 4, sel, hist, candKey, candIdx, srv);
  kF2 <<<SRVCAP / 64, 64, 0, stream>>>(box, ph, pw, sel, srv, out, topScore, obox);
  kG  <<<TOPK, 256, 0, stream>>>(obox, masks);
  kH  <<<1, 256, 0, stream>>>(topScore, masks, out);
}

// Round 6
// 194.580 us; speedup vs baseline: 1.0842x; 1.0842x over previous
//
#include <hip/hip_runtime.h>
#include <stdint.h>

#define NUM_CLASSES 80u
#define TOPK 1000
#define CONF_T 0.05f
#define NMS_T 0.6f
#define MAX_COORD 4096.0f
#define TARGET 1152u            // top-1000 + tie/superset slack
#define CAP 49152u              // linear candidate buffer capacity
#define SRVCAP 2048u            // survivor buffer (>= TARGET + boundary ties)
#define STATIC_F 4.0f           // static candidate prefilter threshold
#define STATIC_KEY 0xC0800000u  // fkey(+4.0f)
#define NBINS 4096              // spread bins: (k - STATIC_KEY) >> 13
#define BINSH 13
#define LCAP 512u               // per-block LDS candidate staging (kA)
#define PBLK 1024u              // per-block survivor staging (kSel)

typedef unsigned long long ull;
typedef ull ull2 __attribute__((ext_vector_type(2)));

// Monotone float->uint key: descending float == descending key
__device__ __forceinline__ uint32_t fkey(float x) {
  uint32_t k = __float_as_uint(x);
  return (k & 0x80000000u) ? ~k : (k | 0x80000000u);
}

// Inclusive suffix sum of per-thread v across 256 threads (2 barriers).
__device__ __forceinline__ uint32_t suffix_scan_256(uint32_t v, uint32_t* part,
                                                    int t) {
  int lane = t & 63, wid = t >> 6;  // 4 waves
#pragma unroll
  for (int off = 1; off < 64; off <<= 1) {
    uint32_t x = __shfl_down(v, off);
    if (lane + off < 64) v += x;
  }
  if (lane == 0) part[wid] = v;  // wave totals
  __syncthreads();
  if (wid == 0 && lane < 4) {
    uint32_t pv = part[lane];
#pragma unroll
    for (int off = 1; off < 4; off <<= 1) {
      uint32_t x = __shfl_down(pv, off);
      if (lane + off < 4) pv += x;
    }
    part[lane] = pv;  // inclusive suffix of wave totals
  }
  __syncthreads();
  uint32_t after = (wid < 3) ? part[wid + 1] : 0u;
  return v + after;
}

// Suffix-scan hl[NBINSX] with 256 threads (contiguous chunk per thread) and
// find the crossing bin for `target` (LDS-array variant, fallback path).
template <int NBINSX>
__device__ __forceinline__ void pick_bin(const uint32_t* hl, uint32_t target,
                                         int t, uint32_t* part, uint32_t* binS,
                                         uint32_t* AS, uint32_t* cntS) {
  const int CH = NBINSX / 256;
  uint32_t s = 0;
#pragma unroll
  for (int j = 0; j < CH; ++j) s += hl[t * CH + j];
  uint32_t incl = suffix_scan_256(s, part, t);
  uint32_t after = incl - s;  // suffix strictly after my chunk
  if (incl >= target && after < target) {  // crossing inside my chunk: unique
    uint32_t cum = after;
    for (int j = CH - 1; j >= 0; --j) {
      uint32_t h = hl[t * CH + j];
      if (cum + h >= target) { *binS = (uint32_t)(t * CH + j); *AS = cum; *cntS = h; break; }
      cum += h;
    }
  }
}

// ---------------- kernel Z: zero hist+sel, prefill outputs ----------------
__global__ void __launch_bounds__(256) kz(uint32_t* hist, uint32_t* sel,
                                          float* out, float* topScore) {
  int g = blockIdx.x * 256 + threadIdx.x;  // 16 x 256 = 4096
  hist[g] = 0u;
  if (g < 16) sel[g] = 0u;
  for (int i = g; i < 4000; i += 4096) out[i] = 0.0f;  // boxes prefill
  if (g < 1000) { out[5000 + g] = 0.0f; topScore[g] = 0.0f; }  // labels/scores
}

// ---------------- kernel A: batched-load stream + compact + histogram -----
// r5 post-mortem: 54us invariant to occupancy (16->32 waves) and loads/iter
// (1->2) => MLP-capped, not BW/occupancy. Hypothesis (a): compiler won't
// hoist next loads above the branchy atomic candidate code, so ~2 loads in
// flight/wave at L3-cold latency. Test+fix: explicit software pipeline --
// issue 5 independent float4 loads into named batch regs BEFORE processing
// the previous batch. If null, the cap is per-CU MSHR (hardware floor).
__device__ __forceinline__ void kA_proc1(float f, uint32_t eidx,
                                         uint32_t* __restrict__ sel,
                                         uint32_t* __restrict__ hist,
                                         uint32_t* __restrict__ candKey,
                                         uint32_t* __restrict__ candIdx,
                                         uint32_t* lk, uint32_t* li,
                                         uint32_t* lcnt) {
  if (f >= STATIC_F) {
    uint32_t k = fkey(f);
    uint32_t bb = (k - STATIC_KEY) >> BINSH;
    if (bb > NBINS - 1u) bb = NBINS - 1u;
    atomicAdd(&hist[bb], 1u);
    uint32_t p = atomicAdd(lcnt, 1u);  // LDS atomic: cheap, distributed
    if (p < LCAP) { lk[p] = k; li[p] = eidx; }
    else {  // spill (correctness-only; ~never taken)
      uint32_t gp = atomicAdd(&sel[2], 1u);
      if (gp < CAP) { candKey[gp] = k; candIdx[gp] = eidx; }
    }
  }
}

__global__ void __launch_bounds__(256, 4) kA(const float4* __restrict__ cls,
                                             int n4,
                                             uint32_t* __restrict__ sel,
                                             uint32_t* __restrict__ hist,
                                             uint32_t* __restrict__ candKey,
                                             uint32_t* __restrict__ candIdx) {
  __shared__ uint32_t lk[LCAP];
  __shared__ uint32_t li[LCAP];
  __shared__ uint32_t lcnt, gbase;
  if (threadIdx.x == 0) lcnt = 0u;
  __syncthreads();
  const uint32_t nth = gridDim.x * blockDim.x;
  const uint32_t gid = blockIdx.x * blockDim.x + threadIdx.x;

#define LDB_(R, mo)                                                          \
  _Pragma("unroll") for (int u = 0; u < 5; ++u) R[u] =                       \
      cls[gid + ((mo) + (uint32_t)u) * nth];
#define PROC_(R, mo)                                                         \
  _Pragma("unroll") for (int u = 0; u < 5; ++u) {                            \
    uint32_t e = (gid + ((mo) + (uint32_t)u) * nth) * 4u;                    \
    kA_proc1(R[u].x, e + 0u, sel, hist, candKey, candIdx, lk, li, &lcnt);    \
    kA_proc1(R[u].y, e + 1u, sel, hist, candKey, candIdx, lk, li, &lcnt);    \
    kA_proc1(R[u].z, e + 2u, sel, hist, candKey, candIdx, lk, li, &lcnt);    \
    kA_proc1(R[u].w, e + 3u, sel, hist, candKey, candIdx, lk, li, &lcnt);    \
  }

  if ((uint32_t)n4 % nth == 0u) {  // uniform path (bench: 10 float4/thread)
    const uint32_t T = (uint32_t)n4 / nth;
    const uint32_t nb = T / 5u;  // batches of 5
    float4 A[5], B[5];
    if (nb) LDB_(A, 0u);
    for (uint32_t b = 0; b < nb; b += 2u) {
      bool hasB = (b + 1u < nb);
      if (hasB) LDB_(B, (b + 1u) * 5u);        // issue next loads FIRST
      PROC_(A, b * 5u);                         // then branchy/atomic work
      if (b + 2u < nb) LDB_(A, (b + 2u) * 5u);
      if (hasB) PROC_(B, (b + 1u) * 5u);
    }
    for (uint32_t m = nb * 5u; m < T; ++m) {   // tail (T%5 != 0)
      float4 v = cls[gid + m * nth];
      uint32_t e = (gid + m * nth) * 4u;
      kA_proc1(v.x, e + 0u, sel, hist, candKey, candIdx, lk, li, &lcnt);
      kA_proc1(v.y, e + 1u, sel, hist, candKey, candIdx, lk, li, &lcnt);
      kA_proc1(v.z, e + 2u, sel, hist, candKey, candIdx, lk, li, &lcnt);
      kA_proc1(v.w, e + 3u, sel, hist, candKey, candIdx, lk, li, &lcnt);
    }
  } else {  // generic fallback (any n4)
    for (uint32_t i = gid; i < (uint32_t)n4; i += nth) {
      float4 v = cls[i];
      uint32_t e = i * 4u;
      kA_proc1(v.x, e + 0u, sel, hist, candKey, candIdx, lk, li, &lcnt);
      kA_proc1(v.y, e + 1u, sel, hist, candKey, candIdx, lk, li, &lcnt);
      kA_proc1(v.z, e + 2u, sel, hist, candKey, candIdx, lk, li, &lcnt);
      kA_proc1(v.w, e + 3u, sel, hist, candKey, candIdx, lk, li, &lcnt);
    }
  }
#undef LDB_
#undef PROC_
  __syncthreads();
  uint32_t c = lcnt; if (c > LCAP) c = LCAP;
  if (threadIdx.x == 0 && c) gbase = atomicAdd(&sel[2], c);  // ONE per block
  __syncthreads();
  for (uint32_t i = threadIdx.x; i < c; i += 256u) {
    uint32_t gp = gbase + i;
    if (gp < CAP) { candKey[gp] = lk[i]; candIdx[gp] = li[i]; }
  }
}

// ---------------- kernel Sel: multi-block threshold + survivor select -----
// 64 blocks. Fast path: thread t reads its 16 hist bins DIRECTLY from
// global via 4 coalesced uint4 loads (no LDS staging round-trip -- the
// 16 KB hist is freshly written cross-XCD; one vector read per thread is
// the minimal-latency way to get it), register pick_bin, T = bin floor,
// then parallel candidate select (LDS staging + one global atomic/block).
// FALLBACK (n < TARGET or n > CAP; never on bench data): block 0 full scan.
__global__ void __launch_bounds__(256) kSel(
    const float4* __restrict__ cls4, int n4,
    uint32_t* __restrict__ sel, const uint32_t* __restrict__ hist,
    const uint32_t* __restrict__ candKey, const uint32_t* __restrict__ candIdx,
    ull* __restrict__ srv) {
  __shared__ uint32_t hl[NBINS];       // used by fallback only
  __shared__ uint32_t part[16];
  __shared__ uint32_t sk_[PBLK];       // staged survivor keys
  __shared__ uint32_t si_[PBLK];       // staged survivor idxs
  __shared__ uint32_t lcnt, gbase, binS, AS, cntS;
  int t = threadIdx.x;
  uint32_t n = sel[2];
  bool fb = (n < TARGET) || (n > CAP);

  if (!fb) {
    uint32_t hh[16];
    const uint4* h4 = (const uint4*)hist;
#pragma unroll
    for (int q = 0; q < 4; ++q) {
      uint4 v = h4[t * 4 + q];
      hh[q * 4 + 0] = v.x; hh[q * 4 + 1] = v.y;
      hh[q * 4 + 2] = v.z; hh[q * 4 + 3] = v.w;
    }
    if (t == 0) { lcnt = 0u; binS = 0u; AS = 0u; cntS = 0u; }
    uint32_t s = 0;
#pragma unroll
    for (int j = 0; j < 16; ++j) s += hh[j];
    uint32_t incl = suffix_scan_256(s, part, t);  // internal barriers order init
    uint32_t after = incl - s;
    if (incl >= TARGET && after < TARGET) {       // unique crossing thread
      uint32_t cum = after;
#pragma unroll
      for (int j = 15; j >= 0; --j) {
        if (cum + hh[j] >= TARGET) {
          binS = (uint32_t)(t * 16 + j); AS = cum; cntS = hh[j]; break;
        }
        cum += hh[j];
      }
    }
    __syncthreads();
    uint32_t T;
    if (AS + cntS > SRVCAP)            // bin spike (adversarial ties only):
      T = STATIC_KEY + ((binS + 1u) << BINSH);  // take strictly-above set (=AS)
    else
      T = STATIC_KEY + (binS << BINSH);
    uint32_t stride = gridDim.x * blockDim.x;
    for (uint32_t i = blockIdx.x * 256u + (uint32_t)t; i < n; i += stride) {
      uint32_t k = candKey[i];
      if (k >= T) {
        uint32_t p = atomicAdd(&lcnt, 1u);
        if (p < PBLK) { sk_[p] = k; si_[p] = candIdx[i]; }
      }
    }
    __syncthreads();
    uint32_t c = lcnt; if (c > PBLK) c = PBLK;
    if (t == 0 && c) gbase = atomicAdd(&sel[4], c);  // ONE per block
    __syncthreads();
    for (uint32_t i = t; i < c; i += 256u) {
      uint32_t k = sk_[i];
      float x = __uint_as_float(k & 0x7fffffffu);  // all candidates positive
      float p = 1.0f / (1.0f + expf(-x));          // fp32 sigmoid
      uint32_t pos = gbase + i;
      if (pos < SRVCAP)
        srv[pos] = ((ull)__float_as_uint(p) << 32) | (ull)(uint32_t)(~si_[i]);
    }
  } else {
    if (blockIdx.x != 0) return;
    // ---- single-block full fallback ----
    for (int i = t; i < NBINS; i += 256) hl[i] = 0u;
    if (t == 0) { binS = 0u; AS = 0u; cntS = 0u; }
    __syncthreads();
    for (int i = t; i < n4; i += 256) {
      float4 v = cls4[i];
      atomicAdd(&hl[fkey(v.x) >> 20], 1u);
      atomicAdd(&hl[fkey(v.y) >> 20], 1u);
      atomicAdd(&hl[fkey(v.z) >> 20], 1u);
      atomicAdd(&hl[fkey(v.w) >> 20], 1u);
    }
    __syncthreads();
    pick_bin<NBINS>(hl, TARGET, t, part, &binS, &AS, &cntS);  // coarse k>>20
    __syncthreads();
    uint32_t b20 = binS, A = AS;
    for (int i = t; i < 1024; i += 256) hl[i] = 0u;
    if (t == 0) { binS = 0u; }
    __syncthreads();
    for (int i = t; i < n4; i += 256) {  // fine 10-bit hist within b20
      float4 v = cls4[i];
      uint32_t k4[4] = {fkey(v.x), fkey(v.y), fkey(v.z), fkey(v.w)};
#pragma unroll
      for (int c2 = 0; c2 < 4; ++c2)
        if ((k4[c2] >> 20) == b20) atomicAdd(&hl[(k4[c2] >> 10) & 1023u], 1u);
    }
    __syncthreads();
    uint32_t rem = TARGET - A;  // >= 1; fine total = hl-sum >= rem
    pick_bin<1024>(hl, rem, t, part, &binS, &AS, &cntS);
    __syncthreads();
    uint32_t T = (b20 << 20) | (binS << 10);
    for (int i = t; i < n4; i += 256) {
      float4 v = cls4[i];
      uint32_t k4[4] = {fkey(v.x), fkey(v.y), fkey(v.z), fkey(v.w)};
#pragma unroll
      for (int c2 = 0; c2 < 4; ++c2) {
        uint32_t k = k4[c2];
        if (k >= T) {
          uint32_t pos = atomicAdd(&sel[4], 1u);  // perf-irrelevant path
          if (pos < SRVCAP) {
            float x = (k & 0x80000000u) ? __uint_as_float(k & 0x7fffffffu)
                                        : __uint_as_float(~k);
            float p = 1.0f / (1.0f + expf(-x));
            uint32_t idx = (uint32_t)i * 4u + c2;
            srv[pos] = ((ull)__float_as_uint(p) << 32) | (ull)(uint32_t)(~idx);
          }
        }
      }
    }
  }
}

// ---------------- kernel F2: rank survivors + emit ------------------------
// 8 blocks x 256 (was 32x64: 4x fewer redundant 16 KB survivor stagings).
// Thread i computes rank_i = #{j: skey_j > skey_i} (exact, ull keys unique
// via ~idx low bits) and emits row rank_i. Order-independent.
__global__ void __launch_bounds__(256) kF2(
    const float* __restrict__ box, const int* __restrict__ ph,
    const int* __restrict__ pw, const uint32_t* __restrict__ sel,
    const ull* __restrict__ srv, float* __restrict__ out,
    float* __restrict__ topScore, float* __restrict__ obox) {
  __shared__ __align__(16) ull sk[SRVCAP];
  int t = threadIdx.x;
  uint32_t scount = sel[4]; if (scount > SRVCAP) scount = SRVCAP;
  uint32_t pad = (scount + 1u) & ~1u;
  for (uint32_t i = t; i < pad; i += 256u) sk[i] = (i < scount) ? srv[i] : 0ull;
  __syncthreads();
  uint32_t i = blockIdx.x * 256u + (uint32_t)t;
  if (i >= scount) return;
  ull my = sk[i];
  uint32_t rank = 0;
#pragma unroll 4
  for (uint32_t j = 0; j < pad; j += 2u) {
    ull2 v = *reinterpret_cast<const ull2*>(&sk[j]);  // b128 broadcast read
    rank += (v.x > my) + (v.y > my);
  }
  if (rank >= TOPK) return;
  uint32_t idx = ~(uint32_t)my;
  float p = __uint_as_float((uint32_t)(my >> 32));
  uint32_t label = idx % NUM_CLASSES;
  uint32_t anchor = idx / NUM_CLASSES;
  float W = (float)pw[0], H = (float)ph[0];
  float b0 = box[anchor * 4u + 0u], b1 = box[anchor * 4u + 1u];
  float b2 = box[anchor * 4u + 2u], b3 = box[anchor * 4u + 3u];
  out[rank * 4 + 0] = fminf(fmaxf(b0 / W, 0.0f), 1.0f);
  out[rank * 4 + 1] = fminf(fmaxf(b1 / H, 0.0f), 1.0f);
  out[rank * 4 + 2] = fminf(fmaxf(b2 / W, 0.0f), 1.0f);
  out[rank * 4 + 3] = fminf(fmaxf(b3 / H, 0.0f), 1.0f);
  out[5000 + rank] = (float)label;
  topScore[rank] = p;
  float off = (float)label * MAX_COORD;  // class-aware NMS offset
  obox[rank * 4 + 0] = b0 + off; obox[rank * 4 + 1] = b1 + off;
  obox[rank * 4 + 2] = b2 + off; obox[rank * 4 + 3] = b3 + off;
}

// ---------------- kernel G: IoU bitmasks (j > i) + per-row summary --------
// rowsum[i] bit g = (mask word g of row i nonzero). Lets kH skip staging
// the ~90% of the 128 KB mask matrix that is all-zero.
__global__ void kG(const float* __restrict__ obox, ull* __restrict__ masks,
                   uint32_t* __restrict__ rowsum) {
  __shared__ uint32_t rsS;
  int i = blockIdx.x;  // row 0..999
  if (threadIdx.x == 0) rsS = 0u;
  __syncthreads();
  float x1i = obox[i * 4 + 0], y1i = obox[i * 4 + 1];
  float x2i = obox[i * 4 + 2], y2i = obox[i * 4 + 3];
  float ai = (x2i - x1i) * (y2i - y1i);
  for (int base = 0; base < 1024; base += 256) {
    int jj = base + (int)threadIdx.x;
    bool bit = false;
    if (jj < TOPK && jj > i) {
      float x1j = obox[jj * 4 + 0], y1j = obox[jj * 4 + 1];
      float x2j = obox[jj * 4 + 2], y2j = obox[jj * 4 + 3];
      float aj = (x2j - x1j) * (y2j - y1j);
      float ix1 = fmaxf(x1i, x1j), iy1 = fmaxf(y1i, y1j);
      float ix2 = fminf(x2i, x2j), iy2 = fminf(y2i, y2j);
      float iw = fmaxf(ix2 - ix1, 0.0f), ih = fmaxf(iy2 - iy1, 0.0f);
      float inter = iw * ih;
      float iou = inter / (ai + aj - inter + 1e-9f);
      bit = iou > NMS_T;
    }
    ull m = __ballot(bit);
    if ((threadIdx.x & 63u) == 0u) {
      masks[i * 16 + (jj >> 6)] = m;
      if (m) atomicOr(&rsS, 1u << (jj >> 6));
    }
  }
  __syncthreads();
  if (threadIdx.x == 0) rowsum[i] = rsS;
}

// ---------------- kernel H: LDS-staged single-wave greedy NMS -------------
__global__ void __launch_bounds__(256) kH(const float* __restrict__ topScore,
                                          const ull* __restrict__ masks,
                                          const uint32_t* __restrict__ rowsum,
                                          float* __restrict__ out) {
  __shared__ ull lmask[TOPK * 16];
  __shared__ uint32_t rsL[TOPK];
  __shared__ ull keepsh[16];
  int t = threadIdx.x;
  for (int i = t; i < TOPK; i += 256) rsL[i] = rowsum[i];
  if (t < 16) keepsh[t] = 0ull;
  __syncthreads();
  for (int i = t; i < TOPK * 16; i += 256) {  // stage only nonzero words
    lmask[i] = ((rsL[i >> 4] >> (i & 15)) & 1u) ? masks[i] : 0ull;
  }
  for (int base = 0; base < 1024; base += 256) {
    int r = base + t;
    bool v = (r < TOPK) && (topScore[r] > CONF_T);
    ull b = __ballot(v);
    if ((t & 63) == 0) keepsh[(base >> 6) + (t >> 6)] = b;
  }
  __syncthreads();
  if (t < 64) {  // single-wave greedy loop, no barriers inside
    ull kw = (t < 16) ? keepsh[t] : 0ull;
    ull nzw = 0ull;
    if (t < 16) {
      for (int b = 0; b < 64; ++b) {
        int r = t * 64 + b;
        if (r < TOPK && rsL[r]) nzw |= 1ull << b;
      }
    }
    for (int w = 0; w < 16; ++w) {
      ull cur = __shfl(kw, w) & __shfl(nzw, w);
      while (cur) {
        int b = __ffsll((long long)cur) - 1;
        int i = w * 64 + b;
        if (t < 16) kw &= ~lmask[i * 16 + t];  // row i suppresses only j > i
        ull nk = __shfl(kw, w);
        cur = nk & __shfl(nzw, w);
        cur &= (b == 63) ? 0ull : (~0ull << (b + 1));
      }
    }
    if (t < 16) keepsh[t] = kw;
  }
  __syncthreads();
  for (int r = t; r < TOPK; r += 256) {
    bool k = (keepsh[r >> 6] >> (r & 63)) & 1ull;
    float s = topScore[r];
    out[4000 + r] = k ? s : 0.0f;
    out[6000 + r] = k ? 1.0f : 0.0f;
  }
}

extern "C" void kernel_launch(void* const* d_in, const int* in_sizes, int n_in,
                              void* d_out, int out_size, void* d_ws, size_t ws_size,
                              hipStream_t stream) {
  const float* cls = (const float*)d_in[0];  // (1, N, 80) logits
  const float* box = (const float*)d_in[1];  // (1, N, 4)
  const int* ph = (const int*)d_in[2];       // img_h
  const int* pw = (const int*)d_in[3];       // img_w
  float* out = (float*)d_out;                // [boxes 4000 | scores 1000 | labels 1000 | keep 1000]
  int n = in_sizes[0];                       // 20,971,520 (divisible by 4)

  uint8_t* w = (uint8_t*)d_ws;
  uint32_t* hist    = (uint32_t*)(w);                               // 16 KB
  uint32_t* sel     = (uint32_t*)(w + 16384);                       // 64 B (pad 4 KB)
  uint32_t* candKey = (uint32_t*)(w + 20480);                       // 192 KB
  uint32_t* candIdx = (uint32_t*)(w + 20480 + (size_t)CAP * 4);     // 192 KB
  ull*      srv     = (ull*)     (w + 20480 + (size_t)CAP * 8);     // 16 KB
  float*    topScore= (float*)   (w + 20480 + (size_t)CAP * 8 + 16384);          // 4 KB
  float*    obox    = (float*)   (w + 20480 + (size_t)CAP * 8 + 16384 + 4096);   // 16 KB
  ull*      masks   = (ull*)     (w + 20480 + (size_t)CAP * 8 + 16384 + 4096 + 16384); // 128 KB
  uint32_t* rowsum  = (uint32_t*)(w + 20480 + (size_t)CAP * 8 + 16384 + 4096 + 16384 + 131072); // 4 KB

  kz  <<<16, 256, 0, stream>>>(hist, sel, out, topScore);
  kA  <<<2048, 256, 0, stream>>>((const float4*)cls, n / 4, sel, hist, candKey, candIdx);
  kSel<<<64, 256, 0, stream>>>((const float4*)cls, n / 4, sel, hist, candKey, candIdx, srv);
  kF2 <<<SRVCAP / 256, 256, 0, stream>>>(box, ph, pw, sel, srv, out, topScore, obox);
  kG  <<<TOPK, 256, 0, stream>>>(obox, masks, rowsum);
  kH  <<<1, 256, 0, stream>>>(topScore, masks, rowsum, out);
}

// Round 7
// 192.521 us; speedup vs baseline: 1.0958x; 1.0107x over previous
//
#include <hip/hip_runtime.h>
#include <stdint.h>

#define NUM_CLASSES 80u
#define TOPK 1000
#define CONF_T 0.05f
#define NMS_T 0.6f
#define MAX_COORD 4096.0f
#define TARGET 1152u            // top-1000 + tie/superset slack
#define CAP 49152u              // linear candidate buffer capacity
#define SRVCAP 2048u            // survivor buffer (>= TARGET + boundary ties)
#define STATIC_F 4.0f           // static candidate prefilter threshold
#define STATIC_KEY 0xC0800000u  // fkey(+4.0f)
#define NBINS 4096              // spread bins: (k - STATIC_KEY) >> 13
#define BINSH 13
#define LCAP 512u               // per-block LDS candidate staging (kA)
#define PBLK 1024u              // per-block survivor staging (kSel)

typedef unsigned long long ull;
typedef ull ull2 __attribute__((ext_vector_type(2)));

// Monotone float->uint key: descending float == descending key
__device__ __forceinline__ uint32_t fkey(float x) {
  uint32_t k = __float_as_uint(x);
  return (k & 0x80000000u) ? ~k : (k | 0x80000000u);
}

// Inclusive suffix sum of per-thread v across 256 threads (2 barriers).
__device__ __forceinline__ uint32_t suffix_scan_256(uint32_t v, uint32_t* part,
                                                    int t) {
  int lane = t & 63, wid = t >> 6;  // 4 waves
#pragma unroll
  for (int off = 1; off < 64; off <<= 1) {
    uint32_t x = __shfl_down(v, off);
    if (lane + off < 64) v += x;
  }
  if (lane == 0) part[wid] = v;  // wave totals
  __syncthreads();
  if (wid == 0 && lane < 4) {
    uint32_t pv = part[lane];
#pragma unroll
    for (int off = 1; off < 4; off <<= 1) {
      uint32_t x = __shfl_down(pv, off);
      if (lane + off < 4) pv += x;
    }
    part[lane] = pv;  // inclusive suffix of wave totals
  }
  __syncthreads();
  uint32_t after = (wid < 3) ? part[wid + 1] : 0u;
  return v + after;
}

// Suffix-scan hl[NBINSX] with 256 threads (contiguous chunk per thread) and
// find the crossing bin for `target`: unique thread writes bin/A/cnt.
// A = count strictly above bin; cnt = hl[bin]; A < target <= A + cnt.
template <int NBINSX>
__device__ __forceinline__ void pick_bin(const uint32_t* hl, uint32_t target,
                                         int t, uint32_t* part, uint32_t* binS,
                                         uint32_t* AS, uint32_t* cntS) {
  const int CH = NBINSX / 256;
  uint32_t s = 0;
#pragma unroll
  for (int j = 0; j < CH; ++j) s += hl[t * CH + j];
  uint32_t incl = suffix_scan_256(s, part, t);
  uint32_t after = incl - s;  // suffix strictly after my chunk
  if (incl >= target && after < target) {  // crossing inside my chunk: unique
    uint32_t cum = after;
    for (int j = CH - 1; j >= 0; --j) {
      uint32_t h = hl[t * CH + j];
      if (cum + h >= target) { *binS = (uint32_t)(t * CH + j); *AS = cum; *cntS = h; break; }
      cum += h;
    }
  }
}

// ---------------- kernel Z: zero sel, prefill outputs ---------------------
__global__ void __launch_bounds__(256) kz(uint32_t* sel, float* out,
                                          float* topScore) {
  int g = blockIdx.x * 256 + threadIdx.x;  // 16 x 256 = 4096
  if (g < 16) sel[g] = 0u;
  for (int i = g; i < 4000; i += 4096) out[i] = 0.0f;  // boxes prefill
  if (g < 1000) { out[5000 + g] = 0.0f; topScore[g] = 0.0f; }  // labels/scores
}

// ---------------- kernel A: pure stream + static compact ------------------
// r6 post-mortem: kA invariant at ~53-56us across occupancy/ILP changes,
// but the r1 variant WITHOUT the global histogram ran ~17us (serial-chain
// ledger: r1 G+kA+67=232.6 vs r4 G+53+8=210.2). The ~28K device-scope
// hist atomics concentrate on a few 128B lines (logistic tail) and bounce
// those lines across all 8 non-coherent XCD L2s -- tens of us of
// serialization that throttles the whole stream. Fix: NO global histogram
// here; kSel rebuilds it redundantly per-block in LDS from the compact
// candidate array. kA = float4 grid-stride, LDS candidate staging, ONE
// global atomicAdd per block.
__global__ void __launch_bounds__(256) kA(const float4* __restrict__ cls, int n4,
                                          uint32_t* __restrict__ sel,
                                          uint32_t* __restrict__ candKey,
                                          uint32_t* __restrict__ candIdx) {
  __shared__ uint32_t lk[LCAP];       // local candidate keys
  __shared__ uint32_t li[LCAP];       // local candidate idxs
  __shared__ uint32_t lcnt, gbase;
  if (threadIdx.x == 0) lcnt = 0u;
  __syncthreads();
  int stride = gridDim.x * blockDim.x;
  for (int i = blockIdx.x * blockDim.x + threadIdx.x; i < n4; i += stride) {
    float4 v = cls[i];
    float f4[4] = {v.x, v.y, v.z, v.w};
#pragma unroll
    for (int c = 0; c < 4; ++c) {
      if (f4[c] >= STATIC_F) {
        uint32_t p = atomicAdd(&lcnt, 1u);  // LDS atomic: cheap, distributed
        if (p < LCAP) { lk[p] = fkey(f4[c]); li[p] = (uint32_t)i * 4u + c; }
        else {  // spill (correctness-only path; ~never taken)
          uint32_t gp = atomicAdd(&sel[2], 1u);
          if (gp < CAP) { candKey[gp] = fkey(f4[c]); candIdx[gp] = (uint32_t)i * 4u + c; }
        }
      }
    }
  }
  __syncthreads();
  uint32_t c = lcnt; if (c > LCAP) c = LCAP;
  if (threadIdx.x == 0 && c) gbase = atomicAdd(&sel[2], c);  // ONE per block
  __syncthreads();
  for (uint32_t i = threadIdx.x; i < c; i += 256u) {
    uint32_t gp = gbase + i;
    if (gp < CAP) { candKey[gp] = lk[i]; candIdx[gp] = li[i]; }
  }
}

// ---------------- kernel Sel: multi-block threshold + survivor select -----
// 64 blocks. Fast path: each block REDUNDANTLY histograms the ~28K compact
// candidate keys into a 4096-bin LDS hist (112 KB coalesced uint4 read +
// ~110 LDS atomics/thread -- no cross-block coupling, no cross-XCD atomic
// line bounce), picks the crossing bin (T = bin floor; bin width ~4e-3 in
// x, TARGET slack absorbs the whole bin), then selects its 1/64 slice of
// candidates (LDS staging + one global atomic/block). Survivor order is
// arbitrary; kF2's ranking is order-independent.
// FALLBACK (n < TARGET or n > CAP; never on bench data): block 0 full scan.
__global__ void __launch_bounds__(256) kSel(
    const float4* __restrict__ cls4, int n4,
    uint32_t* __restrict__ sel,
    const uint32_t* __restrict__ candKey, const uint32_t* __restrict__ candIdx,
    ull* __restrict__ srv) {
  __shared__ uint32_t hl[NBINS];       // 16 KB
  __shared__ uint32_t part[16];
  __shared__ uint32_t sk_[PBLK];       // staged survivor keys
  __shared__ uint32_t si_[PBLK];       // staged survivor idxs
  __shared__ uint32_t lcnt, gbase, binS, AS, cntS;
  int t = threadIdx.x;
  uint32_t n = sel[2];
  bool fb = (n < TARGET) || (n > CAP);

  if (!fb) {
    for (int i = t; i < NBINS; i += 256) hl[i] = 0u;
    if (t == 0) { lcnt = 0u; binS = 0u; AS = 0u; cntS = 0u; }
    __syncthreads();
    // ---- per-block LDS histogram over all candidate keys ----
    const uint4* ck4 = (const uint4*)candKey;
    uint32_t n4c = n >> 2;
    for (uint32_t i = t; i < n4c; i += 256u) {
      uint4 kv = ck4[i];
      uint32_t b0 = (kv.x - STATIC_KEY) >> BINSH; if (b0 > NBINS - 1u) b0 = NBINS - 1u;
      uint32_t b1 = (kv.y - STATIC_KEY) >> BINSH; if (b1 > NBINS - 1u) b1 = NBINS - 1u;
      uint32_t b2 = (kv.z - STATIC_KEY) >> BINSH; if (b2 > NBINS - 1u) b2 = NBINS - 1u;
      uint32_t b3 = (kv.w - STATIC_KEY) >> BINSH; if (b3 > NBINS - 1u) b3 = NBINS - 1u;
      atomicAdd(&hl[b0], 1u); atomicAdd(&hl[b1], 1u);
      atomicAdd(&hl[b2], 1u); atomicAdd(&hl[b3], 1u);
    }
    for (uint32_t i = (n4c << 2) + (uint32_t)t; i < n; i += 256u) {  // tail 0..3
      uint32_t b = (candKey[i] - STATIC_KEY) >> BINSH;
      if (b > NBINS - 1u) b = NBINS - 1u;
      atomicAdd(&hl[b], 1u);
    }
    __syncthreads();
    pick_bin<NBINS>(hl, TARGET, t, part, &binS, &AS, &cntS);
    __syncthreads();
    uint32_t T;
    if (AS + cntS > SRVCAP)            // bin spike (adversarial ties only):
      T = STATIC_KEY + ((binS + 1u) << BINSH);  // take strictly-above set (=AS)
    else
      T = STATIC_KEY + (binS << BINSH);
    uint32_t stride = gridDim.x * blockDim.x;
    for (uint32_t i = blockIdx.x * 256u + (uint32_t)t; i < n; i += stride) {
      uint32_t k = candKey[i];
      if (k >= T) {
        uint32_t p = atomicAdd(&lcnt, 1u);
        if (p < PBLK) { sk_[p] = k; si_[p] = candIdx[i]; }
      }
    }
    __syncthreads();
    uint32_t c = lcnt; if (c > PBLK) c = PBLK;
    if (t == 0 && c) gbase = atomicAdd(&sel[4], c);  // ONE per block
    __syncthreads();
    for (uint32_t i = t; i < c; i += 256u) {
      uint32_t k = sk_[i];
      float x = __uint_as_float(k & 0x7fffffffu);  // all candidates positive
      float p = 1.0f / (1.0f + expf(-x));          // fp32 sigmoid
      uint32_t pos = gbase + i;
      if (pos < SRVCAP)
        srv[pos] = ((ull)__float_as_uint(p) << 32) | (ull)(uint32_t)(~si_[i]);
    }
  } else {
    if (blockIdx.x != 0) return;
    // ---- single-block full fallback ----
    for (int i = t; i < NBINS; i += 256) hl[i] = 0u;
    if (t == 0) { binS = 0u; AS = 0u; cntS = 0u; }
    __syncthreads();
    for (int i = t; i < n4; i += 256) {
      float4 v = cls4[i];
      atomicAdd(&hl[fkey(v.x) >> 20], 1u);
      atomicAdd(&hl[fkey(v.y) >> 20], 1u);
      atomicAdd(&hl[fkey(v.z) >> 20], 1u);
      atomicAdd(&hl[fkey(v.w) >> 20], 1u);
    }
    __syncthreads();
    pick_bin<NBINS>(hl, TARGET, t, part, &binS, &AS, &cntS);  // coarse k>>20
    __syncthreads();
    uint32_t b20 = binS, A = AS;
    for (int i = t; i < 1024; i += 256) hl[i] = 0u;
    if (t == 0) { binS = 0u; }
    __syncthreads();
    for (int i = t; i < n4; i += 256) {  // fine 10-bit hist within b20
      float4 v = cls4[i];
      uint32_t k4[4] = {fkey(v.x), fkey(v.y), fkey(v.z), fkey(v.w)};
#pragma unroll
      for (int c2 = 0; c2 < 4; ++c2)
        if ((k4[c2] >> 20) == b20) atomicAdd(&hl[(k4[c2] >> 10) & 1023u], 1u);
    }
    __syncthreads();
    uint32_t rem = TARGET - A;  // >= 1; fine total = hl-sum >= rem
    pick_bin<1024>(hl, rem, t, part, &binS, &AS, &cntS);
    __syncthreads();
    uint32_t T = (b20 << 20) | (binS << 10);
    for (int i = t; i < n4; i += 256) {
      float4 v = cls4[i];
      uint32_t k4[4] = {fkey(v.x), fkey(v.y), fkey(v.z), fkey(v.w)};
#pragma unroll
      for (int c2 = 0; c2 < 4; ++c2) {
        uint32_t k = k4[c2];
        if (k >= T) {
          uint32_t pos = atomicAdd(&sel[4], 1u);  // perf-irrelevant path
          if (pos < SRVCAP) {
            float x = (k & 0x80000000u) ? __uint_as_float(k & 0x7fffffffu)
                                        : __uint_as_float(~k);
            float p = 1.0f / (1.0f + expf(-x));
            uint32_t idx = (uint32_t)i * 4u + c2;
            srv[pos] = ((ull)__float_as_uint(p) << 32) | (ull)(uint32_t)(~idx);
          }
        }
      }
    }
  }
}

// ---------------- kernel F2: rank survivors + emit ------------------------
// 8 blocks x 256. Thread i computes rank_i = #{j: skey_j > skey_i} (exact,
// ull keys unique via ~idx low bits) and emits row rank_i.
__global__ void __launch_bounds__(256) kF2(
    const float* __restrict__ box, const int* __restrict__ ph,
    const int* __restrict__ pw, const uint32_t* __restrict__ sel,
    const ull* __restrict__ srv, float* __restrict__ out,
    float* __restrict__ topScore, float* __restrict__ obox) {
  __shared__ __align__(16) ull sk[SRVCAP];
  int t = threadIdx.x;
  uint32_t scount = sel[4]; if (scount > SRVCAP) scount = SRVCAP;
  uint32_t pad = (scount + 1u) & ~1u;
  for (uint32_t i = t; i < pad; i += 256u) sk[i] = (i < scount) ? srv[i] : 0ull;
  __syncthreads();
  uint32_t i = blockIdx.x * 256u + (uint32_t)t;
  if (i >= scount) return;
  ull my = sk[i];
  uint32_t rank = 0;
#pragma unroll 4
  for (uint32_t j = 0; j < pad; j += 2u) {
    ull2 v = *reinterpret_cast<const ull2*>(&sk[j]);  // b128 broadcast read
    rank += (v.x > my) + (v.y > my);
  }
  if (rank >= TOPK) return;
  uint32_t idx = ~(uint32_t)my;
  float p = __uint_as_float((uint32_t)(my >> 32));
  uint32_t label = idx % NUM_CLASSES;
  uint32_t anchor = idx / NUM_CLASSES;
  float W = (float)pw[0], H = (float)ph[0];
  float b0 = box[anchor * 4u + 0u], b1 = box[anchor * 4u + 1u];
  float b2 = box[anchor * 4u + 2u], b3 = box[anchor * 4u + 3u];
  out[rank * 4 + 0] = fminf(fmaxf(b0 / W, 0.0f), 1.0f);
  out[rank * 4 + 1] = fminf(fmaxf(b1 / H, 0.0f), 1.0f);
  out[rank * 4 + 2] = fminf(fmaxf(b2 / W, 0.0f), 1.0f);
  out[rank * 4 + 3] = fminf(fmaxf(b3 / H, 0.0f), 1.0f);
  out[5000 + rank] = (float)label;
  topScore[rank] = p;
  float off = (float)label * MAX_COORD;  // class-aware NMS offset
  obox[rank * 4 + 0] = b0 + off; obox[rank * 4 + 1] = b1 + off;
  obox[rank * 4 + 2] = b2 + off; obox[rank * 4 + 3] = b3 + off;
}

// ---------------- kernel G: IoU bitmasks (j > i) + per-row summary --------
// rowsum[i] bit g = (mask word g of row i nonzero). Lets kH skip staging
// the ~90% of the 128 KB mask matrix that is all-zero.
__global__ void kG(const float* __restrict__ obox, ull* __restrict__ masks,
                   uint32_t* __restrict__ rowsum) {
  __shared__ uint32_t rsS;
  int i = blockIdx.x;  // row 0..999
  if (threadIdx.x == 0) rsS = 0u;
  __syncthreads();
  float x1i = obox[i * 4 + 0], y1i = obox[i * 4 + 1];
  float x2i = obox[i * 4 + 2], y2i = obox[i * 4 + 3];
  float ai = (x2i - x1i) * (y2i - y1i);
  for (int base = 0; base < 1024; base += 256) {
    int jj = base + (int)threadIdx.x;
    bool bit = false;
    if (jj < TOPK && jj > i) {
      float x1j = obox[jj * 4 + 0], y1j = obox[jj * 4 + 1];
      float x2j = obox[jj * 4 + 2], y2j = obox[jj * 4 + 3];
      float aj = (x2j - x1j) * (y2j - y1j);
      float ix1 = fmaxf(x1i, x1j), iy1 = fmaxf(y1i, y1j);
      float ix2 = fminf(x2i, x2j), iy2 = fminf(y2i, y2j);
      float iw = fmaxf(ix2 - ix1, 0.0f), ih = fmaxf(iy2 - iy1, 0.0f);
      float inter = iw * ih;
      float iou = inter / (ai + aj - inter + 1e-9f);
      bit = iou > NMS_T;
    }
    ull m = __ballot(bit);
    if ((threadIdx.x & 63u) == 0u) {
      masks[i * 16 + (jj >> 6)] = m;
      if (m) atomicOr(&rsS, 1u << (jj >> 6));
    }
  }
  __syncthreads();
  if (threadIdx.x == 0) rowsum[i] = rsS;
}

// ---------------- kernel H: LDS-staged single-wave greedy NMS -------------
__global__ void __launch_bounds__(256) kH(const float* __restrict__ topScore,
                                          const ull* __restrict__ masks,
                                          const uint32_t* __restrict__ rowsum,
                                          float* __restrict__ out) {
  __shared__ ull lmask[TOPK * 16];
  __shared__ uint32_t rsL[TOPK];
  __shared__ ull keepsh[16];
  int t = threadIdx.x;
  for (int i = t; i < TOPK; i += 256) rsL[i] = rowsum[i];
  if (t < 16) keepsh[t] = 0ull;
  __syncthreads();
  for (int i = t; i < TOPK * 16; i += 256) {  // stage only nonzero words
    lmask[i] = ((rsL[i >> 4] >> (i & 15)) & 1u) ? masks[i] : 0ull;
  }
  for (int base = 0; base < 1024; base += 256) {
    int r = base + t;
    bool v = (r < TOPK) && (topScore[r] > CONF_T);
    ull b = __ballot(v);
    if ((t & 63) == 0) keepsh[(base >> 6) + (t >> 6)] = b;
  }
  __syncthreads();
  if (t < 64) {  // single-wave greedy loop, no barriers inside
    ull kw = (t < 16) ? keepsh[t] : 0ull;
    ull nzw = 0ull;
    if (t < 16) {
      for (int b = 0; b < 64; ++b) {
        int r = t * 64 + b;
        if (r < TOPK && rsL[r]) nzw |= 1ull << b;
      }
    }
    for (int w = 0; w < 16; ++w) {
      ull cur = __shfl(kw, w) & __shfl(nzw, w);
      while (cur) {
        int b = __ffsll((long long)cur) - 1;
        int i = w * 64 + b;
        if (t < 16) kw &= ~lmask[i * 16 + t];  // row i suppresses only j > i
        ull nk = __shfl(kw, w);
        cur = nk & __shfl(nzw, w);
        cur &= (b == 63) ? 0ull : (~0ull << (b + 1));
      }
    }
    if (t < 16) keepsh[t] = kw;
  }
  __syncthreads();
  for (int r = t; r < TOPK; r += 256) {
    bool k = (keepsh[r >> 6] >> (r & 63)) & 1ull;
    float s = topScore[r];
    out[4000 + r] = k ? s : 0.0f;
    out[6000 + r] = k ? 1.0f : 0.0f;
  }
}

extern "C" void kernel_launch(void* const* d_in, const int* in_sizes, int n_in,
                              void* d_out, int out_size, void* d_ws, size_t ws_size,
                              hipStream_t stream) {
  const float* cls = (const float*)d_in[0];  // (1, N, 80) logits
  const float* box = (const float*)d_in[1];  // (1, N, 4)
  const int* ph = (const int*)d_in[2];       // img_h
  const int* pw = (const int*)d_in[3];       // img_w
  float* out = (float*)d_out;                // [boxes 4000 | scores 1000 | labels 1000 | keep 1000]
  int n = in_sizes[0];                       // 20,971,520 (divisible by 4)

  uint8_t* w = (uint8_t*)d_ws;
  uint32_t* sel     = (uint32_t*)(w + 16384);                       // 64 B (pad 4 KB)
  uint32_t* candKey = (uint32_t*)(w + 20480);                       // 192 KB
  uint32_t* candIdx = (uint32_t*)(w + 20480 + (size_t)CAP * 4);     // 192 KB
  ull*      srv     = (ull*)     (w + 20480 + (size_t)CAP * 8);     // 16 KB
  float*    topScore= (float*)   (w + 20480 + (size_t)CAP * 8 + 16384);          // 4 KB
  float*    obox    = (float*)   (w + 20480 + (size_t)CAP * 8 + 16384 + 4096);   // 16 KB
  ull*      masks   = (ull*)     (w + 20480 + (size_t)CAP * 8 + 16384 + 4096 + 16384); // 128 KB
  uint32_t* rowsum  = (uint32_t*)(w + 20480 + (size_t)CAP * 8 + 16384 + 4096 + 16384 + 131072); // 4 KB

  kz  <<<16, 256, 0, stream>>>(sel, out, topScore);
  kA  <<<2048, 256, 0, stream>>>((const float4*)cls, n / 4, sel, candKey, candIdx);
  kSel<<<64, 256, 0, stream>>>((const float4*)cls, n / 4, sel, candKey, candIdx, srv);
  kF2 <<<SRVCAP / 256, 256, 0, stream>>>(box, ph, pw, sel, srv, out, topScore, obox);
  kG  <<<TOPK, 256, 0, stream>>>(obox, masks, rowsum);
  kH  <<<1, 256, 0, stream>>>(topScore, masks, rowsum, out);
}